// Round 5
// baseline (253.732 us; speedup 1.0000x reference)
//
#include <hip/hip_runtime.h>
#include <math.h>

#define NCODE 64
#define SIGMA 10.0f
#define LOG2E 1.4426950408889634f
#define BLK 256

// Round-5 main kernel: 1 point/thread, e[64] softmax terms held in REGISTERS
// (constant-indexed fully-unrolled loops only — dynamic indexing forces
// scratch spills, round-1 lesson). Pass 2b's recompute+exp (2 fma + sub +
// v_exp per j per point) collapses to one v_mul. Grid 4096 blocks for
// latency hiding (round-4 was 4 blocks/CU and only 63% VALU-busy).
__global__ __launch_bounds__(BLK, 4) void vq_main1(
    const float* __restrict__ x,
    const float* __restrict__ embed,
    float* __restrict__ out_q,          // [npts*2] fp32
    float* __restrict__ partial)        // [nblk*64] fp32 (d_ws)
{
    __shared__ float4 scode[NCODE];     // (e0, e1, ||e||^2_np, 0)  exact
    __shared__ float4 sfast[NCODE];     // (20*log2e*e0, 20*log2e*e1, -10*log2e*n, 0)
    __shared__ float  sred[BLK / 64][NCODE];

    const int t = threadIdx.x;
    if (t < NCODE) {
        float e0 = embed[2 * t];
        float e1 = embed[2 * t + 1];
        // n_j exactly as np: rn(rn(e0*e0) + rn(e1*e1))
        float n = __fadd_rn(__fmul_rn(e0, e0), __fmul_rn(e1, e1));
        scode[t] = make_float4(e0, e1, n, 0.0f);
        const float k20  = 20.0f * LOG2E;
        const float km10 = -10.0f * LOG2E;
        sfast[t] = make_float4(k20 * e0, k20 * e1, km10 * n, 0.0f);
    }
    __syncthreads();

    const int gid = blockIdx.x * BLK + t;
    const float2* __restrict__ xp = (const float2*)x;
    float2* __restrict__ qp = (float2*)out_q;

    float2 p = xp[gid];
    // s exactly as np: rn(rn(p0*p0) + rn(p1*p1))
    float s = __fadd_rn(__fmul_rn(p.x, p.x), __fmul_rn(p.y, p.y));

    // ---- pass 1: bit-exact logits, max + argmax (first-occurrence ties) ----
    float m = -INFINITY;
    int best = 0;
#pragma unroll 8
    for (int j = 0; j < NCODE; ++j) {
        float4 c = scode[j];
        // np sgemm model (OpenBLAS K=2): dot = fma(p1,e1, rn(p0*e0))
        float dot = fmaf(p.y, c.y, __fmul_rn(p.x, c.x));
        float d = __fadd_rn(fmaf(-2.0f, dot, s), c.z);
        float l = __fmul_rn(-SIGMA, d);
        if (l > m) { m = l; best = j; }
    }

    // ---- straight-through forward value: hard_q = embed[argmax] ----
    {
        float4 cb = scode[best];
        qp[gid] = make_float2(cb.x, cb.y);
    }

    // ---- pass 2: softmax terms kept in registers ----
    const float gref = __fmul_rn(fmaf(10.0f, s, m), LOG2E);
    float e[NCODE];
    float ssum = 0.0f;
#pragma unroll 8
    for (int j = 0; j < NCODE; ++j) {
        float4 f = sfast[j];
        float g = fmaf(p.x, f.x, fmaf(p.y, f.y, f.z));
        float v = __builtin_amdgcn_exp2f(g - gref);
        e[j] = v;
        ssum += v;
    }
    const float inv = __builtin_amdgcn_rcpf(ssum);  // ~1ulp; feeds 1M-mean only
#pragma unroll
    for (int j = 0; j < NCODE; ++j) e[j] = __fmul_rn(e[j], inv);

    // ---- compacted butterfly: 63 shuffles; lane l ends owning wave-sum of bin l ----
    const int lane = t & 63;
#pragma unroll
    for (int step = 32; step >= 1; step >>= 1) {
        const bool upper = (lane & step) != 0;
#pragma unroll
        for (int i = 0; i < step; ++i) {
            float lo = e[i], hi = e[i + step];
            float send = upper ? lo : hi;
            float keep = upper ? hi : lo;
            e[i] = keep + __shfl_xor(send, step, 64);
        }
    }

    // ---- cross-wave combine + coalesced partial write ----
    const int wv = t >> 6;
    sred[wv][lane] = e[0];
    __syncthreads();
    if (t < NCODE) {
        float tot = sred[0][t] + sred[1][t] + sred[2][t] + sred[3][t];
        partial[blockIdx.x * NCODE + t] = tot;
    }
}

// ---- round-4 kernel kept verbatim as ws_size fallback (needs only 256 KB) ----
#define PPT4 4
__global__ __launch_bounds__(BLK, 4) void vq_main4(
    const float* __restrict__ x,
    const float* __restrict__ embed,
    float* __restrict__ out_q,
    float* __restrict__ partial)
{
    __shared__ float4 scode[NCODE];
    __shared__ float4 sfast[NCODE];
    __shared__ float  sred[BLK / 64][NCODE];

    const int t = threadIdx.x;
    if (t < NCODE) {
        float e0 = embed[2 * t];
        float e1 = embed[2 * t + 1];
        float n = __fadd_rn(__fmul_rn(e0, e0), __fmul_rn(e1, e1));
        scode[t] = make_float4(e0, e1, n, 0.0f);
        const float k20  = 20.0f * LOG2E;
        const float km10 = -10.0f * LOG2E;
        sfast[t] = make_float4(k20 * e0, k20 * e1, km10 * n, 0.0f);
    }
    __syncthreads();

    const int gid    = blockIdx.x * BLK + t;
    const int stride = gridDim.x * BLK;
    const float2* __restrict__ xp = (const float2*)x;
    float2* __restrict__ qp = (float2*)out_q;

    float2 p[PPT4]; float s[PPT4]; int idx[PPT4];
#pragma unroll
    for (int k = 0; k < PPT4; ++k) {
        idx[k] = gid + k * stride;
        p[k] = xp[idx[k]];
        s[k] = __fadd_rn(__fmul_rn(p[k].x, p[k].x), __fmul_rn(p[k].y, p[k].y));
    }

    float m[PPT4]; int best[PPT4];
#pragma unroll
    for (int k = 0; k < PPT4; ++k) { m[k] = -INFINITY; best[k] = 0; }
#pragma unroll 8
    for (int j = 0; j < NCODE; ++j) {
        float4 c = scode[j];
#pragma unroll
        for (int k = 0; k < PPT4; ++k) {
            float dot = fmaf(p[k].y, c.y, __fmul_rn(p[k].x, c.x));
            float d = __fadd_rn(fmaf(-2.0f, dot, s[k]), c.z);
            float l = __fmul_rn(-SIGMA, d);
            if (l > m[k]) { m[k] = l; best[k] = j; }
        }
    }
#pragma unroll
    for (int k = 0; k < PPT4; ++k) {
        float4 cb = scode[best[k]];
        qp[idx[k]] = make_float2(cb.x, cb.y);
    }

    float gref[PPT4], ssum[PPT4];
#pragma unroll
    for (int k = 0; k < PPT4; ++k) {
        gref[k] = __fmul_rn(fmaf(10.0f, s[k], m[k]), LOG2E);
        ssum[k] = 0.0f;
    }
#pragma unroll 8
    for (int j = 0; j < NCODE; ++j) {
        float4 f = sfast[j];
#pragma unroll
        for (int k = 0; k < PPT4; ++k) {
            float g = fmaf(p[k].x, f.x, fmaf(p[k].y, f.y, f.z));
            ssum[k] += __builtin_amdgcn_exp2f(g - gref[k]);
        }
    }
#pragma unroll
    for (int k = 0; k < PPT4; ++k)
        gref[k] += __builtin_amdgcn_logf(ssum[k]);

    float acc[NCODE];
#pragma unroll
    for (int j = 0; j < NCODE; ++j) {
        float4 f = sfast[j];
        float tt = 0.0f;
#pragma unroll
        for (int k = 0; k < PPT4; ++k) {
            float g = fmaf(p[k].x, f.x, fmaf(p[k].y, f.y, f.z));
            tt += __builtin_amdgcn_exp2f(g - gref[k]);
        }
        acc[j] = tt;
    }

    const int lane = t & 63;
#pragma unroll
    for (int step = 32; step >= 1; step >>= 1) {
        const bool upper = (lane & step) != 0;
#pragma unroll
        for (int i = 0; i < step; ++i) {
            float lo = acc[i], hi = acc[i + step];
            float send = upper ? lo : hi;
            float keep = upper ? hi : lo;
            acc[i] = keep + __shfl_xor(send, step, 64);
        }
    }
    const int wv = t >> 6;
    sred[wv][lane] = acc[0];
    __syncthreads();
    if (t < NCODE) {
        float tot = sred[0][t] + sred[1][t] + sred[2][t] + sred[3][t];
        partial[blockIdx.x * NCODE + t] = tot;
    }
}

// Stage 2: reduce nblk x 64 partials -> out_lik (no atomics, deterministic).
__global__ __launch_bounds__(256) void vq_reduce(
    const float* __restrict__ partial,
    float* __restrict__ out_lik,
    int nblk, float scale)
{
    __shared__ float sm[4];
    const int b = blockIdx.x;       // bin
    const int t = threadIdx.x;
    float s = 0.0f;
    for (int i = t; i < nblk; i += 256)
        s += partial[i * NCODE + b];
#pragma unroll
    for (int msk = 32; msk >= 1; msk >>= 1)
        s += __shfl_xor(s, msk, 64);
    if ((t & 63) == 0) sm[t >> 6] = s;
    __syncthreads();
    if (t == 0)
        out_lik[b] = (sm[0] + sm[1] + sm[2] + sm[3]) * scale;
}

extern "C" void kernel_launch(void* const* d_in, const int* in_sizes, int n_in,
                              void* d_out, int out_size, void* d_ws, size_t ws_size,
                              hipStream_t stream) {
    (void)n_in;
    const float* x     = (const float*)d_in[0];   // [64*32*32*32] fp32
    const float* embed = (const float*)d_in[1];   // [64*2] fp32

    const int npts = in_sizes[0] / 2;             // 1,048,576 points
    float* out_q   = (float*)d_out;               // [npts*2]
    float* out_lik = (float*)d_out + (out_size - NCODE); // [64] tail
    float* partial = (float*)d_ws;

    const int nblk1 = npts / BLK;                 // 4096 (needs 1 MB ws)
    const size_t need1 = (size_t)nblk1 * NCODE * sizeof(float);

    if (ws_size >= need1) {
        vq_main1<<<nblk1, BLK, 0, stream>>>(x, embed, out_q, partial);
        vq_reduce<<<NCODE, 256, 0, stream>>>(partial, out_lik, nblk1,
                                             1.0f / (float)npts);
    } else {
        const int nblk4 = npts / (BLK * PPT4);    // 1024 (256 KB ws, round-4 proven)
        vq_main4<<<nblk4, BLK, 0, stream>>>(x, embed, out_q, partial);
        vq_reduce<<<NCODE, 256, 0, stream>>>(partial, out_lik, nblk4,
                                             1.0f / (float)npts);
    }
}

// Round 6
// 109.299 us; speedup vs baseline: 2.3214x; 2.3214x over previous
//
#include <hip/hip_runtime.h>
#include <math.h>

#define NCODE 64
#define SIGMA 10.0f
#define LOG2E 1.4426950408889634f
#define BLK 256

// Round-6: identical structure to round-5 but every loop touching e[64] is
// FULLY unrolled. Round-5's "#pragma unroll 8" (partial) on pass 2a left j a
// runtime variable -> e[j] dynamically indexed -> array demoted to scratch
// (VGPR=40, WRITE_SIZE 613 MB of spill traffic). Full unroll keeps e[] in
// registers: peak live set ~90 VGPR < the 128 cap from launch_bounds(256,4).
__global__ __launch_bounds__(BLK, 4) void vq_main1(
    const float* __restrict__ x,
    const float* __restrict__ embed,
    float* __restrict__ out_q,          // [npts*2] fp32
    float* __restrict__ partial)        // [nblk*64] fp32 (d_ws)
{
    __shared__ float4 scode[NCODE];     // (e0, e1, ||e||^2_np, 0)  exact
    __shared__ float4 sfast[NCODE];     // (20*log2e*e0, 20*log2e*e1, -10*log2e*n, 0)
    __shared__ float  sred[BLK / 64][NCODE];

    const int t = threadIdx.x;
    if (t < NCODE) {
        float e0 = embed[2 * t];
        float e1 = embed[2 * t + 1];
        // n_j exactly as np: rn(rn(e0*e0) + rn(e1*e1))
        float n = __fadd_rn(__fmul_rn(e0, e0), __fmul_rn(e1, e1));
        scode[t] = make_float4(e0, e1, n, 0.0f);
        const float k20  = 20.0f * LOG2E;
        const float km10 = -10.0f * LOG2E;
        sfast[t] = make_float4(k20 * e0, k20 * e1, km10 * n, 0.0f);
    }
    __syncthreads();

    const int gid = blockIdx.x * BLK + t;
    const float2* __restrict__ xp = (const float2*)x;
    float2* __restrict__ qp = (float2*)out_q;

    float2 p = xp[gid];
    // s exactly as np: rn(rn(p0*p0) + rn(p1*p1))
    float s = __fadd_rn(__fmul_rn(p.x, p.x), __fmul_rn(p.y, p.y));

    // ---- pass 1: bit-exact logits, max + argmax (first-occurrence ties) ----
    // (scalars only -> partial unroll is fine and keeps I-cache pressure low)
    float m = -INFINITY;
    int best = 0;
#pragma unroll 8
    for (int j = 0; j < NCODE; ++j) {
        float4 c = scode[j];
        // np sgemm model (OpenBLAS K=2): dot = fma(p1,e1, rn(p0*e0))
        float dot = fmaf(p.y, c.y, __fmul_rn(p.x, c.x));
        float d = __fadd_rn(fmaf(-2.0f, dot, s), c.z);
        float l = __fmul_rn(-SIGMA, d);
        if (l > m) { m = l; best = j; }
    }

    // ---- straight-through forward value: hard_q = embed[argmax] ----
    {
        float4 cb = scode[best];
        qp[gid] = make_float2(cb.x, cb.y);
    }

    // ---- pass 2: softmax terms kept in registers (FULL unroll: e[] must
    // never see a runtime index) ----
    const float gref = __fmul_rn(fmaf(10.0f, s, m), LOG2E);
    float e[NCODE];
    float ssum = 0.0f;
#pragma unroll
    for (int j = 0; j < NCODE; ++j) {
        float4 f = sfast[j];
        float g = fmaf(p.x, f.x, fmaf(p.y, f.y, f.z));
        float v = __builtin_amdgcn_exp2f(g - gref);
        e[j] = v;
        ssum += v;
    }
    const float inv = __builtin_amdgcn_rcpf(ssum);  // ~1ulp; feeds 1M-mean only
#pragma unroll
    for (int j = 0; j < NCODE; ++j) e[j] = __fmul_rn(e[j], inv);

    // ---- compacted butterfly: 63 shuffles; lane l ends owning wave-sum of bin l ----
    const int lane = t & 63;
#pragma unroll
    for (int step = 32; step >= 1; step >>= 1) {
        const bool upper = (lane & step) != 0;
#pragma unroll
        for (int i = 0; i < step; ++i) {
            float lo = e[i], hi = e[i + step];
            float send = upper ? lo : hi;
            float keep = upper ? hi : lo;
            e[i] = keep + __shfl_xor(send, step, 64);
        }
    }

    // ---- cross-wave combine + coalesced partial write ----
    const int wv = t >> 6;
    sred[wv][lane] = e[0];
    __syncthreads();
    if (t < NCODE) {
        float tot = sred[0][t] + sred[1][t] + sred[2][t] + sred[3][t];
        partial[blockIdx.x * NCODE + t] = tot;
    }
}

// ---- round-4 kernel kept verbatim as ws_size fallback (needs only 256 KB) ----
#define PPT4 4
__global__ __launch_bounds__(BLK, 4) void vq_main4(
    const float* __restrict__ x,
    const float* __restrict__ embed,
    float* __restrict__ out_q,
    float* __restrict__ partial)
{
    __shared__ float4 scode[NCODE];
    __shared__ float4 sfast[NCODE];
    __shared__ float  sred[BLK / 64][NCODE];

    const int t = threadIdx.x;
    if (t < NCODE) {
        float e0 = embed[2 * t];
        float e1 = embed[2 * t + 1];
        float n = __fadd_rn(__fmul_rn(e0, e0), __fmul_rn(e1, e1));
        scode[t] = make_float4(e0, e1, n, 0.0f);
        const float k20  = 20.0f * LOG2E;
        const float km10 = -10.0f * LOG2E;
        sfast[t] = make_float4(k20 * e0, k20 * e1, km10 * n, 0.0f);
    }
    __syncthreads();

    const int gid    = blockIdx.x * BLK + t;
    const int stride = gridDim.x * BLK;
    const float2* __restrict__ xp = (const float2*)x;
    float2* __restrict__ qp = (float2*)out_q;

    float2 p[PPT4]; float s[PPT4]; int idx[PPT4];
#pragma unroll
    for (int k = 0; k < PPT4; ++k) {
        idx[k] = gid + k * stride;
        p[k] = xp[idx[k]];
        s[k] = __fadd_rn(__fmul_rn(p[k].x, p[k].x), __fmul_rn(p[k].y, p[k].y));
    }

    float m[PPT4]; int best[PPT4];
#pragma unroll
    for (int k = 0; k < PPT4; ++k) { m[k] = -INFINITY; best[k] = 0; }
#pragma unroll 8
    for (int j = 0; j < NCODE; ++j) {
        float4 c = scode[j];
#pragma unroll
        for (int k = 0; k < PPT4; ++k) {
            float dot = fmaf(p[k].y, c.y, __fmul_rn(p[k].x, c.x));
            float d = __fadd_rn(fmaf(-2.0f, dot, s[k]), c.z);
            float l = __fmul_rn(-SIGMA, d);
            if (l > m[k]) { m[k] = l; best[k] = j; }
        }
    }
#pragma unroll
    for (int k = 0; k < PPT4; ++k) {
        float4 cb = scode[best[k]];
        qp[idx[k]] = make_float2(cb.x, cb.y);
    }

    float gref[PPT4], ssum[PPT4];
#pragma unroll
    for (int k = 0; k < PPT4; ++k) {
        gref[k] = __fmul_rn(fmaf(10.0f, s[k], m[k]), LOG2E);
        ssum[k] = 0.0f;
    }
#pragma unroll 8
    for (int j = 0; j < NCODE; ++j) {
        float4 f = sfast[j];
#pragma unroll
        for (int k = 0; k < PPT4; ++k) {
            float g = fmaf(p[k].x, f.x, fmaf(p[k].y, f.y, f.z));
            ssum[k] += __builtin_amdgcn_exp2f(g - gref[k]);
        }
    }
#pragma unroll
    for (int k = 0; k < PPT4; ++k)
        gref[k] += __builtin_amdgcn_logf(ssum[k]);

    float acc[NCODE];
#pragma unroll
    for (int j = 0; j < NCODE; ++j) {
        float4 f = sfast[j];
        float tt = 0.0f;
#pragma unroll
        for (int k = 0; k < PPT4; ++k) {
            float g = fmaf(p[k].x, f.x, fmaf(p[k].y, f.y, f.z));
            tt += __builtin_amdgcn_exp2f(g - gref[k]);
        }
        acc[j] = tt;
    }

    const int lane = t & 63;
#pragma unroll
    for (int step = 32; step >= 1; step >>= 1) {
        const bool upper = (lane & step) != 0;
#pragma unroll
        for (int i = 0; i < step; ++i) {
            float lo = acc[i], hi = acc[i + step];
            float send = upper ? lo : hi;
            float keep = upper ? hi : lo;
            acc[i] = keep + __shfl_xor(send, step, 64);
        }
    }
    const int wv = t >> 6;
    sred[wv][lane] = acc[0];
    __syncthreads();
    if (t < NCODE) {
        float tot = sred[0][t] + sred[1][t] + sred[2][t] + sred[3][t];
        partial[blockIdx.x * NCODE + t] = tot;
    }
}

// Stage 2: reduce nblk x 64 partials -> out_lik (no atomics, deterministic).
__global__ __launch_bounds__(256) void vq_reduce(
    const float* __restrict__ partial,
    float* __restrict__ out_lik,
    int nblk, float scale)
{
    __shared__ float sm[4];
    const int b = blockIdx.x;       // bin
    const int t = threadIdx.x;
    float s = 0.0f;
    for (int i = t; i < nblk; i += 256)
        s += partial[i * NCODE + b];
#pragma unroll
    for (int msk = 32; msk >= 1; msk >>= 1)
        s += __shfl_xor(s, msk, 64);
    if ((t & 63) == 0) sm[t >> 6] = s;
    __syncthreads();
    if (t == 0)
        out_lik[b] = (sm[0] + sm[1] + sm[2] + sm[3]) * scale;
}

extern "C" void kernel_launch(void* const* d_in, const int* in_sizes, int n_in,
                              void* d_out, int out_size, void* d_ws, size_t ws_size,
                              hipStream_t stream) {
    (void)n_in;
    const float* x     = (const float*)d_in[0];   // [64*32*32*32] fp32
    const float* embed = (const float*)d_in[1];   // [64*2] fp32

    const int npts = in_sizes[0] / 2;             // 1,048,576 points
    float* out_q   = (float*)d_out;               // [npts*2]
    float* out_lik = (float*)d_out + (out_size - NCODE); // [64] tail
    float* partial = (float*)d_ws;

    const int nblk1 = npts / BLK;                 // 4096 (needs 1 MB ws)
    const size_t need1 = (size_t)nblk1 * NCODE * sizeof(float);

    if (ws_size >= need1) {
        vq_main1<<<nblk1, BLK, 0, stream>>>(x, embed, out_q, partial);
        vq_reduce<<<NCODE, 256, 0, stream>>>(partial, out_lik, nblk1,
                                             1.0f / (float)npts);
    } else {
        const int nblk4 = npts / (BLK * PPT4);    // 1024 (256 KB ws, round-4 proven)
        vq_main4<<<nblk4, BLK, 0, stream>>>(x, embed, out_q, partial);
        vq_reduce<<<NCODE, 256, 0, stream>>>(partial, out_lik, nblk4,
                                             1.0f / (float)npts);
    }
}

// Round 7
// 97.071 us; speedup vs baseline: 2.6139x; 1.1260x over previous
//
#include <hip/hip_runtime.h>
#include <math.h>

#define NCODE 64
#define SIGMA 10.0f
#define LOG2E 1.4426950408889634f
#define BLK 256

// Round-7: LDS-pipe was the round-6 bottleneck (128 wave-uniform ds_read_b128
// per wave ~= 54 us/CU of LDS pipe, matching the 52 us kernel). Changes:
//  - codebook read via wave-uniform GLOBAL loads (VMEM pipe idle, embed is
//    512 B and L1-resident) with exact n_j rebuilt inline (3 VALU/j).
//  - merged pass: bit-exact logits l[64] held in registers; softmax terms
//    derived as exp2(fma(l_j, log2e, -m*log2e)) — no second constant stream.
//  - LDS now only the 63-shuffle butterfly + 1 KB sred.
// All loops touching l[] are FULLY unrolled (dynamic index => scratch spill,
// rounds 1/5 lesson).
__global__ __launch_bounds__(BLK, 4) void vq_main(
    const float* __restrict__ x,
    const float* __restrict__ embed,
    float* __restrict__ out_q,          // [npts*2] fp32
    float* __restrict__ partial)        // [nblk*64] fp32 (d_ws)
{
    __shared__ float sred[BLK / 64][NCODE];

    const int t   = threadIdx.x;
    const int gid = blockIdx.x * BLK + t;
    const float2* __restrict__ xp = (const float2*)x;
    const float2* __restrict__ ep = (const float2*)embed;
    float2* __restrict__ qp = (float2*)out_q;

    float2 p = xp[gid];
    // s exactly as np: rn(rn(p0*p0) + rn(p1*p1))
    float s = __fadd_rn(__fmul_rn(p.x, p.x), __fmul_rn(p.y, p.y));

    // ---- merged pass 1: bit-exact logits -> l[64] registers, max + argmax ----
    float l[NCODE];
    float m = -INFINITY;
    int best = 0;
#pragma unroll
    for (int j = 0; j < NCODE; ++j) {
        float2 c = ep[j];                       // wave-uniform global load (L1)
        // n_j exactly as np: rn(rn(e0*e0) + rn(e1*e1))
        float n = __fadd_rn(__fmul_rn(c.x, c.x), __fmul_rn(c.y, c.y));
        // np sgemm model (OpenBLAS K=2): dot = fma(p1,e1, rn(p0*e0))
        float dot = fmaf(p.y, c.y, __fmul_rn(p.x, c.x));
        // d = rn(rn(s - 2*dot) + n); fma(-2,dot,s) rounds once == fsub of exact 2*dot
        float d = __fadd_rn(fmaf(-2.0f, dot, s), n);
        float lj = __fmul_rn(-SIGMA, d);
        l[j] = lj;
        if (lj > m) { m = lj; best = j; }       // strict >: first-occurrence ties
    }

    // ---- straight-through forward value: hard_q = embed[argmax] (L1 gather) ----
    {
        float2 cb = ep[best];
        qp[gid] = make_float2(cb.x, cb.y);
    }

    // ---- softmax terms in-place over l[]: e_j = exp2(l_j*log2e - m*log2e) ----
    const float c1 = __fmul_rn(-m, LOG2E);
    float ssum = 0.0f;
#pragma unroll
    for (int j = 0; j < NCODE; ++j) {
        float v = __builtin_amdgcn_exp2f(fmaf(l[j], LOG2E, c1));
        l[j] = v;
        ssum += v;
    }
    const float inv = __builtin_amdgcn_rcpf(ssum);  // ~1ulp; feeds 1M-mean only
#pragma unroll
    for (int j = 0; j < NCODE; ++j) l[j] = __fmul_rn(l[j], inv);

    // ---- compacted butterfly: 63 shuffles; lane k ends owning wave-sum of bin k ----
    const int lane = t & 63;
#pragma unroll
    for (int step = 32; step >= 1; step >>= 1) {
        const bool upper = (lane & step) != 0;
#pragma unroll
        for (int i = 0; i < step; ++i) {
            float lo = l[i], hi = l[i + step];
            float send = upper ? lo : hi;
            float keep = upper ? hi : lo;
            l[i] = keep + __shfl_xor(send, step, 64);
        }
    }

    // ---- cross-wave combine + coalesced partial write ----
    const int wv = t >> 6;
    sred[wv][lane] = l[0];
    __syncthreads();
    if (t < NCODE) {
        float tot = sred[0][t] + sred[1][t] + sred[2][t] + sred[3][t];
        partial[blockIdx.x * NCODE + t] = tot;
    }
}

// ---- round-4 kernel kept verbatim as small-ws fallback (needs 256 KB) ----
#define PPT4 4
__global__ __launch_bounds__(BLK, 4) void vq_main4(
    const float* __restrict__ x,
    const float* __restrict__ embed,
    float* __restrict__ out_q,
    float* __restrict__ partial)
{
    __shared__ float4 scode[NCODE];
    __shared__ float4 sfast[NCODE];
    __shared__ float  sred[BLK / 64][NCODE];

    const int t = threadIdx.x;
    if (t < NCODE) {
        float e0 = embed[2 * t];
        float e1 = embed[2 * t + 1];
        float n = __fadd_rn(__fmul_rn(e0, e0), __fmul_rn(e1, e1));
        scode[t] = make_float4(e0, e1, n, 0.0f);
        const float k20  = 20.0f * LOG2E;
        const float km10 = -10.0f * LOG2E;
        sfast[t] = make_float4(k20 * e0, k20 * e1, km10 * n, 0.0f);
    }
    __syncthreads();

    const int gid    = blockIdx.x * BLK + t;
    const int stride = gridDim.x * BLK;
    const float2* __restrict__ xp = (const float2*)x;
    float2* __restrict__ qp = (float2*)out_q;

    float2 p[PPT4]; float s[PPT4]; int idx[PPT4];
#pragma unroll
    for (int k = 0; k < PPT4; ++k) {
        idx[k] = gid + k * stride;
        p[k] = xp[idx[k]];
        s[k] = __fadd_rn(__fmul_rn(p[k].x, p[k].x), __fmul_rn(p[k].y, p[k].y));
    }

    float m[PPT4]; int best[PPT4];
#pragma unroll
    for (int k = 0; k < PPT4; ++k) { m[k] = -INFINITY; best[k] = 0; }
#pragma unroll 8
    for (int j = 0; j < NCODE; ++j) {
        float4 c = scode[j];
#pragma unroll
        for (int k = 0; k < PPT4; ++k) {
            float dot = fmaf(p[k].y, c.y, __fmul_rn(p[k].x, c.x));
            float d = __fadd_rn(fmaf(-2.0f, dot, s[k]), c.z);
            float lg = __fmul_rn(-SIGMA, d);
            if (lg > m[k]) { m[k] = lg; best[k] = j; }
        }
    }
#pragma unroll
    for (int k = 0; k < PPT4; ++k) {
        float4 cb = scode[best[k]];
        qp[idx[k]] = make_float2(cb.x, cb.y);
    }

    float gref[PPT4], ssum[PPT4];
#pragma unroll
    for (int k = 0; k < PPT4; ++k) {
        gref[k] = __fmul_rn(fmaf(10.0f, s[k], m[k]), LOG2E);
        ssum[k] = 0.0f;
    }
#pragma unroll 8
    for (int j = 0; j < NCODE; ++j) {
        float4 f = sfast[j];
#pragma unroll
        for (int k = 0; k < PPT4; ++k) {
            float g = fmaf(p[k].x, f.x, fmaf(p[k].y, f.y, f.z));
            ssum[k] += __builtin_amdgcn_exp2f(g - gref[k]);
        }
    }
#pragma unroll
    for (int k = 0; k < PPT4; ++k)
        gref[k] += __builtin_amdgcn_logf(ssum[k]);

    float acc[NCODE];
#pragma unroll
    for (int j = 0; j < NCODE; ++j) {
        float4 f = sfast[j];
        float tt = 0.0f;
#pragma unroll
        for (int k = 0; k < PPT4; ++k) {
            float g = fmaf(p[k].x, f.x, fmaf(p[k].y, f.y, f.z));
            tt += __builtin_amdgcn_exp2f(g - gref[k]);
        }
        acc[j] = tt;
    }

    const int lane = t & 63;
#pragma unroll
    for (int step = 32; step >= 1; step >>= 1) {
        const bool upper = (lane & step) != 0;
#pragma unroll
        for (int i = 0; i < step; ++i) {
            float lo = acc[i], hi = acc[i + step];
            float send = upper ? lo : hi;
            float keep = upper ? hi : lo;
            acc[i] = keep + __shfl_xor(send, step, 64);
        }
    }
    const int wv = t >> 6;
    sred[wv][lane] = acc[0];
    __syncthreads();
    if (t < NCODE) {
        float tot = sred[0][t] + sred[1][t] + sred[2][t] + sred[3][t];
        partial[blockIdx.x * NCODE + t] = tot;
    }
}

// Stage 2: reduce nblk x 64 partials -> out_lik (no atomics, deterministic).
__global__ __launch_bounds__(256) void vq_reduce(
    const float* __restrict__ partial,
    float* __restrict__ out_lik,
    int nblk, float scale)
{
    __shared__ float sm[4];
    const int b = blockIdx.x;       // bin
    const int t = threadIdx.x;
    float s = 0.0f;
    for (int i = t; i < nblk; i += 256)
        s += partial[i * NCODE + b];
#pragma unroll
    for (int msk = 32; msk >= 1; msk >>= 1)
        s += __shfl_xor(s, msk, 64);
    if ((t & 63) == 0) sm[t >> 6] = s;
    __syncthreads();
    if (t == 0)
        out_lik[b] = (sm[0] + sm[1] + sm[2] + sm[3]) * scale;
}

extern "C" void kernel_launch(void* const* d_in, const int* in_sizes, int n_in,
                              void* d_out, int out_size, void* d_ws, size_t ws_size,
                              hipStream_t stream) {
    (void)n_in;
    const float* x     = (const float*)d_in[0];   // [64*32*32*32] fp32
    const float* embed = (const float*)d_in[1];   // [64*2] fp32

    const int npts = in_sizes[0] / 2;             // 1,048,576 points
    float* out_q   = (float*)d_out;               // [npts*2]
    float* out_lik = (float*)d_out + (out_size - NCODE); // [64] tail
    float* partial = (float*)d_ws;

    const int nblk1 = npts / BLK;                 // 4096 (needs 1 MB ws)
    const size_t need1 = (size_t)nblk1 * NCODE * sizeof(float);

    if (ws_size >= need1) {
        vq_main<<<nblk1, BLK, 0, stream>>>(x, embed, out_q, partial);
        vq_reduce<<<NCODE, 256, 0, stream>>>(partial, out_lik, nblk1,
                                             1.0f / (float)npts);
    } else {
        const int nblk4 = npts / (BLK * PPT4);    // 1024 (256 KB ws, round-4 proven)
        vq_main4<<<nblk4, BLK, 0, stream>>>(x, embed, out_q, partial);
        vq_reduce<<<NCODE, 256, 0, stream>>>(partial, out_lik, nblk4,
                                             1.0f / (float)npts);
    }
}

// Round 8
// 89.701 us; speedup vs baseline: 2.8286x; 1.0822x over previous
//
#include <hip/hip_runtime.h>
#include <math.h>

#define NCODE 64
#define SIGMA 10.0f
#define LOG2E 1.4426950408889634f
#define BLK 256
#define PPT 2

// Round-8: R7 was VALU-issue-bound at the real (~1.2 GHz) clock. Cuts:
//  - PPT=2, both points' ops written pairwise (SLP -> v_pk_*_f32; pk rounds
//    identically to scalar, pass-1 argmax stays bit-exact vs numpy).
//  - single fused pass: no max-subtraction (logits <= ~0 so exp2 can't
//    overflow; underflow flushes only negligible terms -> softmax ratio
//    unaffected). Deletes the entire second 64-iter exp pass.
//  - codebook via wave-uniform global loads (R7 win); butterfly + n_j
//    amortized over 2 points.
// All loops touching register arrays FULLY unrolled (dynamic index =>
// scratch demotion, rounds 1/5 lesson).
__global__ __launch_bounds__(BLK, 3) void vq_main(
    const float* __restrict__ x,
    const float* __restrict__ embed,
    float* __restrict__ out_q,          // [npts*2] fp32
    float* __restrict__ partial)        // [nblk*64] fp32 (d_ws)
{
    __shared__ float sred[BLK / 64][NCODE];

    const int t      = threadIdx.x;
    const int gid    = blockIdx.x * BLK + t;
    const int stride = gridDim.x * BLK;          // 524288
    const float2* __restrict__ xp = (const float2*)x;
    const float2* __restrict__ ep = (const float2*)embed;
    float2* __restrict__ qp = (float2*)out_q;

    const int i1 = gid;
    const int i2 = gid + stride;
    float2 p1 = xp[i1];
    float2 p2 = xp[i2];
    // s exactly as np: rn(rn(p0*p0) + rn(p1*p1))
    float s1 = __fadd_rn(__fmul_rn(p1.x, p1.x), __fmul_rn(p1.y, p1.y));
    float s2 = __fadd_rn(__fmul_rn(p2.x, p2.x), __fmul_rn(p2.y, p2.y));

    // ---- fused pass: bit-exact logit -> argmax track + inline exp ----
    float2 e[NCODE];                    // (.x = point1 term, .y = point2 term)
    float m1 = -INFINITY, m2 = -INFINITY;
    int b1 = 0, b2 = 0;
    float ss1 = 0.0f, ss2 = 0.0f;
#pragma unroll
    for (int j = 0; j < NCODE; ++j) {
        float2 c = ep[j];               // wave-uniform global load (L1/K$)
        // n_j exactly as np: rn(rn(e0*e0) + rn(e1*e1)) — shared by both points
        float n = __fadd_rn(__fmul_rn(c.x, c.x), __fmul_rn(c.y, c.y));
        // np sgemm model (OpenBLAS K=2): dot = fma(p1,e1, rn(p0*e0))
        float dot1 = fmaf(p1.y, c.y, __fmul_rn(p1.x, c.x));
        float dot2 = fmaf(p2.y, c.y, __fmul_rn(p2.x, c.x));
        float d1 = __fadd_rn(fmaf(-2.0f, dot1, s1), n);
        float d2 = __fadd_rn(fmaf(-2.0f, dot2, s2), n);
        float l1 = __fmul_rn(-SIGMA, d1);
        float l2 = __fmul_rn(-SIGMA, d2);
        if (l1 > m1) { m1 = l1; b1 = j; }   // strict >: first-occurrence ties
        if (l2 > m2) { m2 = l2; b2 = j; }
        // softmax terms without max-sub (l <= ~0: no overflow; underflow ok)
        float v1 = __builtin_amdgcn_exp2f(__fmul_rn(l1, LOG2E));
        float v2 = __builtin_amdgcn_exp2f(__fmul_rn(l2, LOG2E));
        e[j] = make_float2(v1, v2);
        ss1 += v1;
        ss2 += v2;
    }

    // ---- straight-through forward value: hard_q = embed[argmax] ----
    {
        float2 cb1 = ep[b1];
        float2 cb2 = ep[b2];
        qp[i1] = cb1;
        qp[i2] = cb2;
    }

    // guard: if every term underflowed (prob ~0), contribute 0 instead of NaN
    const float inv1 = ss1 > 0.0f ? __builtin_amdgcn_rcpf(ss1) : 0.0f;
    const float inv2 = ss2 > 0.0f ? __builtin_amdgcn_rcpf(ss2) : 0.0f;

    // ---- normalize + merge the two points' contributions ----
    float mg[NCODE];
#pragma unroll
    for (int j = 0; j < NCODE; ++j)
        mg[j] = fmaf(e[j].y, inv2, __fmul_rn(e[j].x, inv1));

    // ---- compacted butterfly: 63 shuffles; lane k ends owning wave-sum of bin k ----
    const int lane = t & 63;
#pragma unroll
    for (int step = 32; step >= 1; step >>= 1) {
        const bool upper = (lane & step) != 0;
#pragma unroll
        for (int i = 0; i < step; ++i) {
            float lo = mg[i], hi = mg[i + step];
            float send = upper ? lo : hi;
            float keep = upper ? hi : lo;
            mg[i] = keep + __shfl_xor(send, step, 64);
        }
    }

    // ---- cross-wave combine + coalesced partial write ----
    const int wv = t >> 6;
    sred[wv][lane] = mg[0];
    __syncthreads();
    if (t < NCODE) {
        float tot = sred[0][t] + sred[1][t] + sred[2][t] + sred[3][t];
        partial[blockIdx.x * NCODE + t] = tot;
    }
}

// ---- round-4 kernel kept verbatim as small-ws fallback (needs 256 KB) ----
#define PPT4 4
__global__ __launch_bounds__(BLK, 4) void vq_main4(
    const float* __restrict__ x,
    const float* __restrict__ embed,
    float* __restrict__ out_q,
    float* __restrict__ partial)
{
    __shared__ float4 scode[NCODE];
    __shared__ float4 sfast[NCODE];
    __shared__ float  sred[BLK / 64][NCODE];

    const int t = threadIdx.x;
    if (t < NCODE) {
        float e0 = embed[2 * t];
        float e1 = embed[2 * t + 1];
        float n = __fadd_rn(__fmul_rn(e0, e0), __fmul_rn(e1, e1));
        scode[t] = make_float4(e0, e1, n, 0.0f);
        const float k20  = 20.0f * LOG2E;
        const float km10 = -10.0f * LOG2E;
        sfast[t] = make_float4(k20 * e0, k20 * e1, km10 * n, 0.0f);
    }
    __syncthreads();

    const int gid    = blockIdx.x * BLK + t;
    const int stride = gridDim.x * BLK;
    const float2* __restrict__ xp = (const float2*)x;
    float2* __restrict__ qp = (float2*)out_q;

    float2 p[PPT4]; float s[PPT4]; int idx[PPT4];
#pragma unroll
    for (int k = 0; k < PPT4; ++k) {
        idx[k] = gid + k * stride;
        p[k] = xp[idx[k]];
        s[k] = __fadd_rn(__fmul_rn(p[k].x, p[k].x), __fmul_rn(p[k].y, p[k].y));
    }

    float m[PPT4]; int best[PPT4];
#pragma unroll
    for (int k = 0; k < PPT4; ++k) { m[k] = -INFINITY; best[k] = 0; }
#pragma unroll 8
    for (int j = 0; j < NCODE; ++j) {
        float4 c = scode[j];
#pragma unroll
        for (int k = 0; k < PPT4; ++k) {
            float dot = fmaf(p[k].y, c.y, __fmul_rn(p[k].x, c.x));
            float d = __fadd_rn(fmaf(-2.0f, dot, s[k]), c.z);
            float lg = __fmul_rn(-SIGMA, d);
            if (lg > m[k]) { m[k] = lg; best[k] = j; }
        }
    }
#pragma unroll
    for (int k = 0; k < PPT4; ++k) {
        float4 cb = scode[best[k]];
        qp[idx[k]] = make_float2(cb.x, cb.y);
    }

    float gref[PPT4], ssum[PPT4];
#pragma unroll
    for (int k = 0; k < PPT4; ++k) {
        gref[k] = __fmul_rn(fmaf(10.0f, s[k], m[k]), LOG2E);
        ssum[k] = 0.0f;
    }
#pragma unroll 8
    for (int j = 0; j < NCODE; ++j) {
        float4 f = sfast[j];
#pragma unroll
        for (int k = 0; k < PPT4; ++k) {
            float g = fmaf(p[k].x, f.x, fmaf(p[k].y, f.y, f.z));
            ssum[k] += __builtin_amdgcn_exp2f(g - gref[k]);
        }
    }
#pragma unroll
    for (int k = 0; k < PPT4; ++k)
        gref[k] += __builtin_amdgcn_logf(ssum[k]);

    float acc[NCODE];
#pragma unroll
    for (int j = 0; j < NCODE; ++j) {
        float4 f = sfast[j];
        float tt = 0.0f;
#pragma unroll
        for (int k = 0; k < PPT4; ++k) {
            float g = fmaf(p[k].x, f.x, fmaf(p[k].y, f.y, f.z));
            tt += __builtin_amdgcn_exp2f(g - gref[k]);
        }
        acc[j] = tt;
    }

    const int lane = t & 63;
#pragma unroll
    for (int step = 32; step >= 1; step >>= 1) {
        const bool upper = (lane & step) != 0;
#pragma unroll
        for (int i = 0; i < step; ++i) {
            float lo = acc[i], hi = acc[i + step];
            float send = upper ? lo : hi;
            float keep = upper ? hi : lo;
            acc[i] = keep + __shfl_xor(send, step, 64);
        }
    }
    const int wv = t >> 6;
    sred[wv][lane] = acc[0];
    __syncthreads();
    if (t < NCODE) {
        float tot = sred[0][t] + sred[1][t] + sred[2][t] + sred[3][t];
        partial[blockIdx.x * NCODE + t] = tot;
    }
}

// Stage 2: reduce nblk x 64 partials -> out_lik (no atomics, deterministic).
__global__ __launch_bounds__(256) void vq_reduce(
    const float* __restrict__ partial,
    float* __restrict__ out_lik,
    int nblk, float scale)
{
    __shared__ float sm[4];
    const int b = blockIdx.x;       // bin
    const int t = threadIdx.x;
    float s = 0.0f;
    for (int i = t; i < nblk; i += 256)
        s += partial[i * NCODE + b];
#pragma unroll
    for (int msk = 32; msk >= 1; msk >>= 1)
        s += __shfl_xor(s, msk, 64);
    if ((t & 63) == 0) sm[t >> 6] = s;
    __syncthreads();
    if (t == 0)
        out_lik[b] = (sm[0] + sm[1] + sm[2] + sm[3]) * scale;
}

extern "C" void kernel_launch(void* const* d_in, const int* in_sizes, int n_in,
                              void* d_out, int out_size, void* d_ws, size_t ws_size,
                              hipStream_t stream) {
    (void)n_in;
    const float* x     = (const float*)d_in[0];   // [64*32*32*32] fp32
    const float* embed = (const float*)d_in[1];   // [64*2] fp32

    const int npts = in_sizes[0] / 2;             // 1,048,576 points
    float* out_q   = (float*)d_out;               // [npts*2]
    float* out_lik = (float*)d_out + (out_size - NCODE); // [64] tail
    float* partial = (float*)d_ws;

    const int nblk = npts / (BLK * PPT);          // 2048 (needs 512 KB ws)
    const size_t need = (size_t)nblk * NCODE * sizeof(float);

    if (ws_size >= need) {
        vq_main<<<nblk, BLK, 0, stream>>>(x, embed, out_q, partial);
        vq_reduce<<<NCODE, 256, 0, stream>>>(partial, out_lik, nblk,
                                             1.0f / (float)npts);
    } else {
        const int nblk4 = npts / (BLK * PPT4);    // 1024 (256 KB ws, round-4 proven)
        vq_main4<<<nblk4, BLK, 0, stream>>>(x, embed, out_q, partial);
        vq_reduce<<<NCODE, 256, 0, stream>>>(partial, out_lik, nblk4,
                                             1.0f / (float)npts);
    }
}